// Round 11
// baseline (853.698 us; speedup 1.0000x reference)
//
#include <hip/hip_runtime.h>

#define N_NODES 50000
#define N_EDGES 800000
#define F_INK   256
#define HC      512   // H*C = 8*64
#define OUT_C   40
#define OUT_P   48    // padded cols for GEMM2 epilogue
#define NEG     0.2f
#define CAP     64    // fixed edge-bucket capacity per dst (max degree ~40 << 64)
#define GEMM_NB 782   // (N_NODES+63)/64
#define CHUNKS  782   // edge chunks of 1024 (256 thr x 4 edges)
#define PART_SZ 6250  // 50000 / 8 dst partitions
#define SCAT_NB (CHUNKS * 8)
#define GRID_F  768   // fused kernel grid: exactly 3 blocks/CU on 256 CUs (co-resident)
#define P1_NV   (GEMM_NB + SCAT_NB)
#define P2_NV   (N_NODES / 16)
#define P3_NV   (N_NODES / 4)

typedef short short8 __attribute__((ext_vector_type(8)));
typedef float f32x4 __attribute__((ext_vector_type(4)));
typedef float f32x2 __attribute__((ext_vector_type(2)));

__device__ __forceinline__ float bf2f(unsigned short u) {
    union { unsigned int i; float f; } v; v.i = ((unsigned int)u) << 16; return v.f;
}
__device__ __forceinline__ unsigned short f2bf(float f) {
    union { float f; unsigned int i; } v; v.f = f;
    unsigned int x = v.i;
    return (unsigned short)((x + 0x7fffu + ((x >> 16) & 1u)) >> 16);
}
__device__ __forceinline__ float bflo(unsigned int u) {
    union { unsigned int i; float f; } v; v.i = u << 16; return v.f;
}
__device__ __forceinline__ float bfhi(unsigned int u) {
    union { unsigned int i; float f; } v; v.i = u & 0xffff0000u; return v.f;
}
__device__ __forceinline__ bool ei_is64(const int* ei) {
    return ei[1] == 0 && ei[3] == 0 && ei[5] == 0;
}
// exact for 0<NEG<1 (2 VALU)
__device__ __forceinline__ float lrelu(float x) { return fmaxf(x, NEG * x); }
__device__ __forceinline__ unsigned char f2fp8(float v) {
    return (unsigned char)(__builtin_amdgcn_cvt_pk_fp8_f32(v, v, 0, false) & 0xff);
}
__device__ __forceinline__ float fp82f(unsigned char b) {
    f32x2 p = __builtin_amdgcn_cvt_pk_f32_fp8((int)b, false);
    return p[0];
}

// Grid barrier (G16 pattern): all GRID_F blocks are co-resident by construction.
// Release: __threadfence (agent-scope -> L2 writeback) before arrive; acquire:
// __threadfence after observing full count (L2 inv). Counters zeroed by prep_k.
__device__ __forceinline__ void gridbar(int* bar) {
    __syncthreads();
    if (threadIdx.x == 0) {
        __threadfence();
        atomicAdd(bar, 1);
        while (atomicAdd(bar, 0) < (int)gridDim.x) __builtin_amdgcn_s_sleep(8);
        __threadfence();
    }
    __syncthreads();
}

// ---------------- prep: pack W1/W2 + canon small + zero padded cnt + zero barriers ------
__global__ __launch_bounds__(256) void prep_k(const float* __restrict__ W1, const float* __restrict__ W2,
                       const float* __restrict__ s1, const float* __restrict__ d1, const float* __restrict__ b1,
                       const float* __restrict__ s2, const float* __restrict__ d2, const float* __restrict__ b2,
                       unsigned short* __restrict__ W1p, unsigned short* __restrict__ W2p,
                       unsigned short* __restrict__ s1c, unsigned short* __restrict__ d1c,
                       unsigned short* __restrict__ b1c, unsigned short* __restrict__ s2c,
                       unsigned short* __restrict__ d2c, unsigned short* __restrict__ b2c,
                       int* __restrict__ cnt, int* __restrict__ bar) {
    int b = blockIdx.x, tid = threadIdx.x;
    if (b < 512) {
        int t = b * 256 + tid;                    // < 131072 = F_INK*HC
        int k = t / HC, n = t % HC;
        int s = k >> 5, q = (k >> 3) & 3, j = k & 7;
        W1p[((((s << 2) + q) * HC + n) << 3) + j] = f2bf(W1[k * HC + n]);
    } else if (b < 608) {
        int t = (b - 512) * 256 + tid;            // < 24576 = HC*OUT_P
        int k = t / OUT_P, n = t % OUT_P;
        int s = k >> 5, q = (k >> 3) & 3, j = k & 7;
        unsigned short v = (n < OUT_C) ? f2bf(W2[k * OUT_C + n]) : (unsigned short)0;
        W2p[((((s << 2) + q) * OUT_P + n) << 3) + j] = v;
    } else if (b == 608) {
        for (int j = tid; j < 512; j += 256) {
            s1c[j] = f2bf(s1[j]); d1c[j] = f2bf(d1[j]); b1c[j] = f2bf(b1[j]);
        }
        if (tid < OUT_C) { s2c[tid] = f2bf(s2[tid]); d2c[tid] = f2bf(d2[tid]); b2c[tid] = f2bf(b2[tid]); }
        if (tid >= 64 && tid < 66) bar[tid - 64] = 0;   // zero the 2 grid-barrier counters
    } else {
        int i = (b - 609) * 256 + tid;
        if (i < N_NODES) cnt[i * 16] = 0;   // one counter per 64B line; self-loop implicit
    }
}

// ---------------- FUSED persistent kernel: P1 (GEMM1+scatter) | P2 (agg1) | P3 (agg2) ----
#define ACC16(u, wgt)                                                              \
    {                                                                              \
        f32x2 q0 = __builtin_amdgcn_cvt_pk_f32_fp8((int)(u).x, false);             \
        f32x2 q1 = __builtin_amdgcn_cvt_pk_f32_fp8((int)(u).x, true);              \
        f32x2 q2 = __builtin_amdgcn_cvt_pk_f32_fp8((int)(u).y, false);             \
        f32x2 q3 = __builtin_amdgcn_cvt_pk_f32_fp8((int)(u).y, true);              \
        f32x2 q4 = __builtin_amdgcn_cvt_pk_f32_fp8((int)(u).z, false);             \
        f32x2 q5 = __builtin_amdgcn_cvt_pk_f32_fp8((int)(u).z, true);              \
        f32x2 q6 = __builtin_amdgcn_cvt_pk_f32_fp8((int)(u).w, false);             \
        f32x2 q7 = __builtin_amdgcn_cvt_pk_f32_fp8((int)(u).w, true);              \
        f32x2 wv = {(wgt), (wgt)};                                                 \
        ac[0] += wv * q0; ac[1] += wv * q1; ac[2] += wv * q2; ac[3] += wv * q3;    \
        ac[4] += wv * q4; ac[5] += wv * q5; ac[6] += wv * q6; ac[7] += wv * q7;    \
    }

__global__ __launch_bounds__(256, 3) void fused_k(const float* __restrict__ x,
                       const unsigned short* __restrict__ Wp,
                       const unsigned short* __restrict__ a_s, const unsigned short* __restrict__ a_d,
                       unsigned char* __restrict__ h1f8,
                       float* __restrict__ as1, float* __restrict__ ad1,
                       const int* __restrict__ ei, int* __restrict__ cnt, int* __restrict__ srcs,
                       const unsigned short* __restrict__ b1,
                       const unsigned short* __restrict__ W2p,
                       const unsigned short* __restrict__ a_s2, const unsigned short* __restrict__ a_d2,
                       unsigned char* __restrict__ h2f8,
                       const unsigned short* __restrict__ b2, float* __restrict__ outp,
                       int* __restrict__ bar) {
    __shared__ __align__(16) char smem[33792];   // union: GEMM xs | agg1 rows+sSrc | agg2 sSrc+sCnt
    __shared__ int sCnt[16];
    __shared__ float sAs[16], sAd[16];
    __shared__ int ctr;
    int tid = threadIdx.x;
    int w = tid >> 6, lane = tid & 63;

    // =============== P1: GEMM1+alpha1 tiles (0..781) + scatter tiles (782..) ===============
    for (int vt = blockIdx.x; vt < P1_NV; vt += gridDim.x) {
        if (vt >= GEMM_NB) {
            // ---- scatter tile ----
            int sb = vt - GEMM_NB;
            int part = sb & 7;
            int chunk = sb >> 3;
            int lo = part * PART_SZ;
            bool is64 = ei_is64(ei);
            int e0 = chunk * 1024 + (tid << 2);
            int s[4], d[4];
            bool vld[4];
            if (chunk < CHUNKS - 1) {
                if (is64) {
                    int4 a0 = *reinterpret_cast<const int4*>(ei + 2 * e0);
                    int4 a1 = *reinterpret_cast<const int4*>(ei + 2 * e0 + 4);
                    int4 c0 = *reinterpret_cast<const int4*>(ei + 2 * N_EDGES + 2 * e0);
                    int4 c1 = *reinterpret_cast<const int4*>(ei + 2 * N_EDGES + 2 * e0 + 4);
                    s[0] = a0.x; s[1] = a0.z; s[2] = a1.x; s[3] = a1.z;
                    d[0] = c0.x; d[1] = c0.z; d[2] = c1.x; d[3] = c1.z;
                } else {
                    int4 a0 = *reinterpret_cast<const int4*>(ei + e0);
                    int4 c0 = *reinterpret_cast<const int4*>(ei + N_EDGES + e0);
                    s[0] = a0.x; s[1] = a0.y; s[2] = a0.z; s[3] = a0.w;
                    d[0] = c0.x; d[1] = c0.y; d[2] = c0.z; d[3] = c0.w;
                }
                vld[0] = vld[1] = vld[2] = vld[3] = true;
            } else {
#pragma unroll
                for (int j = 0; j < 4; j++) {
                    int e = e0 + j;
                    vld[j] = e < N_EDGES;
                    int ec = vld[j] ? e : 0;
                    s[j] = is64 ? ei[2 * ec] : ei[ec];
                    d[j] = is64 ? ei[2 * N_EDGES + 2 * ec] : ei[N_EDGES + ec];
                }
            }
#pragma unroll
            for (int j = 0; j < 4; j++) {
                int dj = d[j];
                if (vld[j] && dj >= lo && dj < lo + PART_SZ) {
                    int pos = atomicAdd(&cnt[dj * 16], 1);
                    if (pos < CAP) srcs[(size_t)dj * CAP + pos] = s[j];
                }
            }
            __syncthreads();
            continue;
        }
        // ---- GEMM tile ----
        {
            unsigned short* xs = reinterpret_cast<unsigned short*>(smem);   // 64 x 264 bf16
            int row0 = vt * 64;
#pragma unroll
            for (int it = 0; it < 16; it++) {
                int j = tid + it * 256;
                int r = j >> 6;
                int c = (j & 63) << 2;
                int rr = row0 + r; rr = rr < N_NODES ? rr : N_NODES - 1;
                float4 f = *reinterpret_cast<const float4*>(x + (size_t)rr * F_INK + c);
                unsigned int lo = (unsigned int)f2bf(f.x) | ((unsigned int)f2bf(f.y) << 16);
                unsigned int hi = (unsigned int)f2bf(f.z) | ((unsigned int)f2bf(f.w) << 16);
                *reinterpret_cast<uint2*>(&xs[r * 264 + c]) = make_uint2(lo, hi);
            }
            __syncthreads();
            int q = lane >> 4, l16 = lane & 15;
            short8 a[8];
#pragma unroll
            for (int s = 0; s < 8; s++)
                a[s] = *reinterpret_cast<const short8*>(&xs[(w * 16 + l16) * 264 + s * 32 + q * 8]);
            int orow = row0 + w * 16 + q * 4;
#pragma unroll
            for (int bn = 0; bn < 8; bn++) {
                f32x4 acc[4];
#pragma unroll
                for (int t = 0; t < 4; t++) acc[t] = (f32x4){0.f, 0.f, 0.f, 0.f};
#pragma unroll
                for (int s = 0; s < 8; s++) {
#pragma unroll
                    for (int t = 0; t < 4; t++) {
                        int col = bn * 64 + t * 16 + l16;
                        short8 b = *reinterpret_cast<const short8*>(Wp + ((((s << 2) + q) * HC + col) << 3));
                        acc[t] = __builtin_amdgcn_mfma_f32_16x16x32_bf16(a[s], b, acc[t], 0, 0, 0);
                    }
                }
                float sa0 = 0.f, sa1 = 0.f, sa2 = 0.f, sa3 = 0.f;
                float da0 = 0.f, da1 = 0.f, da2 = 0.f, da3 = 0.f;
#pragma unroll
                for (int t = 0; t < 4; t++) {
                    int col = bn * 64 + t * 16 + l16;
                    float asc = bf2f(a_s[col]);
                    float adc = bf2f(a_d[col]);
                    float v0 = acc[t][0], v1 = acc[t][1], v2 = acc[t][2], v3 = acc[t][3];
                    sa0 += v0 * asc; da0 += v0 * adc;
                    sa1 += v1 * asc; da1 += v1 * adc;
                    sa2 += v2 * asc; da2 += v2 * adc;
                    sa3 += v3 * asc; da3 += v3 * adc;
                    if (orow + 3 < N_NODES) {
                        h1f8[(size_t)(orow + 0) * HC + col] = f2fp8(v0);
                        h1f8[(size_t)(orow + 1) * HC + col] = f2fp8(v1);
                        h1f8[(size_t)(orow + 2) * HC + col] = f2fp8(v2);
                        h1f8[(size_t)(orow + 3) * HC + col] = f2fp8(v3);
                    } else {
                        if (orow + 0 < N_NODES) h1f8[(size_t)(orow + 0) * HC + col] = f2fp8(v0);
                        if (orow + 1 < N_NODES) h1f8[(size_t)(orow + 1) * HC + col] = f2fp8(v1);
                        if (orow + 2 < N_NODES) h1f8[(size_t)(orow + 2) * HC + col] = f2fp8(v2);
                        if (orow + 3 < N_NODES) h1f8[(size_t)(orow + 3) * HC + col] = f2fp8(v3);
                    }
                }
#pragma unroll
                for (int m = 1; m < 16; m <<= 1) {
                    sa0 += __shfl_xor(sa0, m, 64); sa1 += __shfl_xor(sa1, m, 64);
                    sa2 += __shfl_xor(sa2, m, 64); sa3 += __shfl_xor(sa3, m, 64);
                    da0 += __shfl_xor(da0, m, 64); da1 += __shfl_xor(da1, m, 64);
                    da2 += __shfl_xor(da2, m, 64); da3 += __shfl_xor(da3, m, 64);
                }
                if (l16 < 4) {
                    int rr = orow + l16;
                    float sav = (l16 == 0) ? sa0 : (l16 == 1) ? sa1 : (l16 == 2) ? sa2 : sa3;
                    float dav = (l16 == 0) ? da0 : (l16 == 1) ? da1 : (l16 == 2) ? da2 : da3;
                    if (rr < N_NODES) { as1[rr * 8 + bn] = sav; ad1[rr * 8 + bn] = dav; }
                }
            }
            __syncthreads();
        }
    }
    gridbar(&bar[0]);

    // =============== P2: agg1 tiles (16 dsts each) ===============
    {
        int half = lane >> 5, li = lane & 31;
        int h = li >> 2;
        uint4 ub0 = reinterpret_cast<const uint4*>(b1)[li * 2 + 0];
        uint4 ub1 = reinterpret_cast<const uint4*>(b1)[li * 2 + 1];
        unsigned short* rows = reinterpret_cast<unsigned short*>(smem);     // 16*520 bf16 = 16640B
        int* sSrc = reinterpret_cast<int*>(smem + 16640);                   // 16*CAP ints = 4096B
        for (int vt = blockIdx.x; vt < P2_NV; vt += gridDim.x) {
            int base = vt * 16;
            reinterpret_cast<int4*>(sSrc)[tid] =
                reinterpret_cast<const int4*>(srcs + (size_t)base * CAP)[tid];
            if (tid < 16) {
                int d = cnt[(base + tid) * 16];
                sCnt[tid] = d < CAP ? d : CAP;
                sAs[tid] = 0.f; sAd[tid] = 0.f;
            }
            if (tid == 0) ctr = 0;
            __syncthreads();
            for (;;) {
                int rl = 0;
                if (lane == 0) rl = atomicAdd(&ctr, 1);
                rl = __shfl(rl, 0, 64);
                if (rl >= 16) break;
                int wid = base + rl;
                float adv = ad1[wid * 8 + h];
                const int* sp = sSrc + rl * CAP;
                int deg = sCnt[rl];
                f32x2 ac[8];
#pragma unroll
                for (int k = 0; k < 8; k++) ac[k] = (f32x2){0.f, 0.f};
                float sumw = 0.f;
                {   // pair 0: half0 = implicit self-loop, half1 = first real edge
                    int s = half ? (deg > 0 ? sp[0] : wid) : wid;
                    float A = as1[s * 8 + h];
                    uint4 u = reinterpret_cast<const uint4*>(h1f8 + (size_t)s * HC)[li];
                    float wj = (half && deg == 0) ? 0.f : __expf(lrelu(A + adv));
                    sumw += wj;
                    ACC16(u, wj)
                }
                int v = 1;
                for (; v + 16 <= deg; v += 16) {
                    int s[8]; float A[8]; uint4 u[8];
#pragma unroll
                    for (int j = 0; j < 8; j++) s[j] = sp[v + 2 * j + half];
#pragma unroll
                    for (int j = 0; j < 8; j++) A[j] = as1[s[j] * 8 + h];
#pragma unroll
                    for (int j = 0; j < 8; j++)
                        u[j] = reinterpret_cast<const uint4*>(h1f8 + (size_t)s[j] * HC)[li];
#pragma unroll
                    for (int j = 0; j < 8; j++) {
                        float wj = __expf(lrelu(A[j] + adv));
                        sumw += wj;
                        ACC16(u[j], wj)
                    }
                }
                for (; v + 8 <= deg; v += 8) {
                    int s[4]; float A[4]; uint4 u[4];
#pragma unroll
                    for (int j = 0; j < 4; j++) s[j] = sp[v + 2 * j + half];
#pragma unroll
                    for (int j = 0; j < 4; j++) A[j] = as1[s[j] * 8 + h];
#pragma unroll
                    for (int j = 0; j < 4; j++)
                        u[j] = reinterpret_cast<const uint4*>(h1f8 + (size_t)s[j] * HC)[li];
#pragma unroll
                    for (int j = 0; j < 4; j++) {
                        float wj = __expf(lrelu(A[j] + adv));
                        sumw += wj;
                        ACC16(u[j], wj)
                    }
                }
                for (; v + 4 <= deg; v += 4) {
                    int s[2]; float A[2]; uint4 u[2];
#pragma unroll
                    for (int j = 0; j < 2; j++) s[j] = sp[v + 2 * j + half];
#pragma unroll
                    for (int j = 0; j < 2; j++) A[j] = as1[s[j] * 8 + h];
#pragma unroll
                    for (int j = 0; j < 2; j++)
                        u[j] = reinterpret_cast<const uint4*>(h1f8 + (size_t)s[j] * HC)[li];
#pragma unroll
                    for (int j = 0; j < 2; j++) {
                        float wj = __expf(lrelu(A[j] + adv));
                        sumw += wj;
                        ACC16(u[j], wj)
                    }
                }
                for (; v < deg; v += 2) {
                    int vv = v + half;
                    bool ok = vv < deg;
                    int s = ok ? sp[vv] : wid;
                    float A = as1[s * 8 + h];
                    uint4 u = reinterpret_cast<const uint4*>(h1f8 + (size_t)s * HC)[li];
                    float wj = ok ? __expf(lrelu(A + adv)) : 0.f;
                    sumw += wj;
                    ACC16(u, wj)
                }
                sumw += __shfl_xor(sumw, 32, 64);
#pragma unroll
                for (int k = 0; k < 8; k++) {
                    ac[k][0] += __shfl_xor(ac[k][0], 32, 64);
                    ac[k][1] += __shfl_xor(ac[k][1], 32, 64);
                }
                float inv = 1.f / sumw;
                f32x2 n0 = half ? ac[4] : ac[0];
                f32x2 n1 = half ? ac[5] : ac[1];
                f32x2 n2 = half ? ac[6] : ac[2];
                f32x2 n3 = half ? ac[7] : ac[3];
                uint4 ubh = half ? ub1 : ub0;
                float o0 = fmaxf(n0[0] * inv + bflo(ubh.x), 0.f);
                float o1 = fmaxf(n0[1] * inv + bfhi(ubh.x), 0.f);
                float o2 = fmaxf(n1[0] * inv + bflo(ubh.y), 0.f);
                float o3 = fmaxf(n1[1] * inv + bfhi(ubh.y), 0.f);
                float o4 = fmaxf(n2[0] * inv + bflo(ubh.z), 0.f);
                float o5 = fmaxf(n2[1] * inv + bfhi(ubh.z), 0.f);
                float o6 = fmaxf(n3[0] * inv + bflo(ubh.w), 0.f);
                float o7 = fmaxf(n3[1] * inv + bfhi(ubh.w), 0.f);
                uint4 r;
                r.x = (unsigned int)f2bf(o0) | ((unsigned int)f2bf(o1) << 16);
                r.y = (unsigned int)f2bf(o2) | ((unsigned int)f2bf(o3) << 16);
                r.z = (unsigned int)f2bf(o4) | ((unsigned int)f2bf(o5) << 16);
                r.w = (unsigned int)f2bf(o6) | ((unsigned int)f2bf(o7) << 16);
                *reinterpret_cast<uint4*>(&rows[rl * 520 + li * 16 + half * 8]) = r;
            }
            __syncthreads();
            // Phase 2: h2[16 x 40] = rows @ W2 (fp8 out, 64B stride) + alpha2 partials.
            if (w < 3) {
                int q = lane >> 4, l16 = lane & 15;
                int col = w * 16 + l16;
                f32x4 acc = (f32x4){0.f, 0.f, 0.f, 0.f};
#pragma unroll
                for (int s = 0; s < HC / 32; s++) {
                    short8 a = *reinterpret_cast<const short8*>(&rows[l16 * 520 + s * 32 + q * 8]);
                    short8 b = *reinterpret_cast<const short8*>(W2p + ((((s << 2) + q) * OUT_P + col) << 3));
                    acc = __builtin_amdgcn_mfma_f32_16x16x32_bf16(a, b, acc, 0, 0, 0);
                }
                float sa0 = 0.f, sa1 = 0.f, sa2 = 0.f, sa3 = 0.f;
                float da0 = 0.f, da1 = 0.f, da2 = 0.f, da3 = 0.f;
                if (col < OUT_C) {
                    float asc = bf2f(a_s2[col]);
                    float adc = bf2f(a_d2[col]);
                    sa0 = acc[0] * asc; da0 = acc[0] * adc;
                    sa1 = acc[1] * asc; da1 = acc[1] * adc;
                    sa2 = acc[2] * asc; da2 = acc[2] * adc;
                    sa3 = acc[3] * asc; da3 = acc[3] * adc;
#pragma unroll
                    for (int r = 0; r < 4; r++)
                        h2f8[(size_t)(base + q * 4 + r) * 64 + col] = f2fp8(acc[r]);
                }
#pragma unroll
                for (int m = 1; m < 16; m <<= 1) {
                    sa0 += __shfl_xor(sa0, m, 64); sa1 += __shfl_xor(sa1, m, 64);
                    sa2 += __shfl_xor(sa2, m, 64); sa3 += __shfl_xor(sa3, m, 64);
                    da0 += __shfl_xor(da0, m, 64); da1 += __shfl_xor(da1, m, 64);
                    da2 += __shfl_xor(da2, m, 64); da3 += __shfl_xor(da3, m, 64);
                }
                if (l16 < 4) {
                    int rr = q * 4 + l16;
                    float sav = (l16 == 0) ? sa0 : (l16 == 1) ? sa1 : (l16 == 2) ? sa2 : sa3;
                    float dav = (l16 == 0) ? da0 : (l16 == 1) ? da1 : (l16 == 2) ? da2 : da3;
                    atomicAdd(&sAs[rr], sav);
                    atomicAdd(&sAd[rr], dav);
                }
            }
            __syncthreads();
            if (tid < 16) {
                unsigned char* r = h2f8 + (size_t)(base + tid) * 64;
                *reinterpret_cast<float*>(r + 40) = sAs[tid];   // alpha2_src logit
                *reinterpret_cast<float*>(r + 44) = sAd[tid];   // alpha2_dst logit
            }
            __syncthreads();
        }
    }
    gridbar(&bar[1]);

    // =============== P3: agg2 tiles (4 dsts each) + log_softmax ===============
    {
        int* sS = reinterpret_cast<int*>(smem);          // 4*CAP ints = 1024B
        int* sC = reinterpret_cast<int*>(smem + 1024);   // 4 ints
        bool act = lane < OUT_C;
        int lclamp = act ? lane : 0;
        float bv = bf2f(b2[lclamp]);
        for (int vt = blockIdx.x; vt < P3_NV; vt += gridDim.x) {
            int base = vt * 4;
            if (tid < 64)
                reinterpret_cast<int4*>(sS)[tid] =
                    reinterpret_cast<const int4*>(srcs + (size_t)base * CAP)[tid];
            if (tid < 4) {
                int d = cnt[(base + tid) * 16];
                sC[tid] = d < CAP ? d : CAP;
            }
            __syncthreads();
            int wid = base + w;
            const unsigned char* rd = h2f8 + (size_t)wid * 64;
            float adv = *reinterpret_cast<const float*>(rd + 44);
            float acc, sumw;
            {   // implicit self-loop
                float w0 = __expf(lrelu(*reinterpret_cast<const float*>(rd + 40) + adv));
                sumw = w0;
                acc = w0 * fp82f(rd[lclamp]);
            }
            const int* sp = sS + w * CAP;
            int deg = sC[w];
            int v = 0;
            for (; v + 8 <= deg; v += 8) {
                const unsigned char* r[8];
                float A[8];
                unsigned char c[8];
#pragma unroll
                for (int j = 0; j < 8; j++) r[j] = h2f8 + (size_t)sp[v + j] * 64;
#pragma unroll
                for (int j = 0; j < 8; j++) A[j] = *reinterpret_cast<const float*>(r[j] + 40);
#pragma unroll
                for (int j = 0; j < 8; j++) c[j] = r[j][lclamp];
#pragma unroll
                for (int j = 0; j < 8; j++) {
                    float wj = __expf(lrelu(A[j] + adv));
                    sumw += wj;
                    acc += wj * fp82f(c[j]);
                }
            }
            for (; v + 4 <= deg; v += 4) {
                const unsigned char* r[4];
                float A[4];
                unsigned char c[4];
#pragma unroll
                for (int j = 0; j < 4; j++) r[j] = h2f8 + (size_t)sp[v + j] * 64;
#pragma unroll
                for (int j = 0; j < 4; j++) A[j] = *reinterpret_cast<const float*>(r[j] + 40);
#pragma unroll
                for (int j = 0; j < 4; j++) c[j] = r[j][lclamp];
#pragma unroll
                for (int j = 0; j < 4; j++) {
                    float wj = __expf(lrelu(A[j] + adv));
                    sumw += wj;
                    acc += wj * fp82f(c[j]);
                }
            }
            for (; v < deg; v++) {
                const unsigned char* r0 = h2f8 + (size_t)sp[v] * 64;
                float w0 = __expf(lrelu(*reinterpret_cast<const float*>(r0 + 40) + adv));
                sumw += w0;
                acc += w0 * fp82f(r0[lclamp]);
            }
            float o = acc / sumw + bv;
            float mval = act ? o : -1e30f;
#pragma unroll
            for (int m = 32; m >= 1; m >>= 1) mval = fmaxf(mval, __shfl_xor(mval, m, 64));
            float ex = act ? __expf(o - mval) : 0.f;
#pragma unroll
            for (int m = 32; m >= 1; m >>= 1) ex += __shfl_xor(ex, m, 64);
            float res = o - mval - __logf(ex);
            if (act) outp[(size_t)wid * OUT_C + lane] = res;
            __syncthreads();
        }
    }
}

extern "C" void kernel_launch(void* const* d_in, const int* in_sizes, int n_in,
                              void* d_out, int out_size, void* d_ws, size_t ws_size,
                              hipStream_t stream) {
    const float* x      = (const float*)d_in[0];
    const int*   ei     = (const int*)d_in[1];
    const float* W1     = (const float*)d_in[2];
    const float* as1raw = (const float*)d_in[3];
    const float* ad1raw = (const float*)d_in[4];
    const float* b1raw  = (const float*)d_in[5];
    const float* W2     = (const float*)d_in[6];
    const float* as2raw = (const float*)d_in[7];
    const float* ad2raw = (const float*)d_in[8];
    const float* b2raw  = (const float*)d_in[9];
    float* out = (float*)d_out;

    char* p = (char*)d_ws;
    auto alloc = [&](size_t bytes) -> char* {
        char* r = p;
        p += (bytes + 255) & ~(size_t)255;
        return r;
    };
    unsigned short* s1c  = (unsigned short*)alloc(512 * 2);
    unsigned short* d1c  = (unsigned short*)alloc(512 * 2);
    unsigned short* b1c  = (unsigned short*)alloc(512 * 2);
    unsigned short* s2c  = (unsigned short*)alloc(OUT_C * 2);
    unsigned short* d2c  = (unsigned short*)alloc(OUT_C * 2);
    unsigned short* b2c  = (unsigned short*)alloc(OUT_C * 2);
    unsigned char*  h1f8 = (unsigned char*)alloc((size_t)N_NODES * HC);        // 25.6 MB
    unsigned char*  h2f8 = (unsigned char*)alloc((size_t)N_NODES * 64);        // 3.2 MB
    float* as1  = (float*)alloc((size_t)N_NODES * 8 * 4);
    float* ad1  = (float*)alloc((size_t)N_NODES * 8 * 4);
    int* cnt    = (int*)alloc((size_t)N_NODES * 64);                           // padded 64B/ctr
    int* srcs   = (int*)alloc((size_t)N_NODES * CAP * 4);                      // 12.8 MB
    int* bar    = (int*)alloc(256);                                            // 2 barrier ctrs
    unsigned short* W1p = (unsigned short*)alloc((size_t)F_INK * HC * 2);
    unsigned short* W2p = (unsigned short*)alloc((size_t)HC * OUT_P * 2);
    (void)ws_size; (void)in_sizes; (void)n_in; (void)out_size;

    const int NB = (N_NODES + 255) / 256;  // 196

    prep_k<<<609 + NB, 256, 0, stream>>>(W1, W2, as1raw, ad1raw, b1raw, as2raw, ad2raw, b2raw,
                                         W1p, W2p, s1c, d1c, b1c, s2c, d2c, b2c, cnt, bar);
    fused_k<<<GRID_F, 256, 0, stream>>>(x, W1p, s1c, d1c, h1f8, as1, ad1,
                                        ei, cnt, srcs, b1c, W2p, s2c, d2c,
                                        h2f8, b2c, out, bar);
}

// Round 12
// 265.914 us; speedup vs baseline: 3.2104x; 3.2104x over previous
//
#include <hip/hip_runtime.h>

#define N_NODES 50000
#define N_EDGES 800000
#define F_INK   256
#define HC      512   // H*C = 8*64
#define OUT_C   40
#define OUT_P   48    // padded cols for GEMM2 epilogue
#define NEG     0.2f
#define CAP     64    // fixed edge-bucket capacity per dst (max degree ~40 << 64)
#define GEMM_NB 782   // (N_NODES+63)/64
#define CHUNKS  782   // edge chunks of 1024 (256 thr x 4 edges)
#define SCAT_NB CHUNKS   // single-pass scatter: each edge handled exactly once

typedef short short8 __attribute__((ext_vector_type(8)));
typedef float f32x4 __attribute__((ext_vector_type(4)));
typedef float f32x2 __attribute__((ext_vector_type(2)));

__device__ __forceinline__ float bf2f(unsigned short u) {
    union { unsigned int i; float f; } v; v.i = ((unsigned int)u) << 16; return v.f;
}
__device__ __forceinline__ unsigned short f2bf(float f) {
    union { float f; unsigned int i; } v; v.f = f;
    unsigned int x = v.i;
    return (unsigned short)((x + 0x7fffu + ((x >> 16) & 1u)) >> 16);
}
__device__ __forceinline__ float bflo(unsigned int u) {
    union { unsigned int i; float f; } v; v.i = u << 16; return v.f;
}
__device__ __forceinline__ float bfhi(unsigned int u) {
    union { unsigned int i; float f; } v; v.i = u & 0xffff0000u; return v.f;
}
__device__ __forceinline__ bool ei_is64(const int* ei) {
    return ei[1] == 0 && ei[3] == 0 && ei[5] == 0;
}
// exact for 0<NEG<1: x>0 -> max(x,NEG*x)=x ; x<=0 -> max(x,NEG*x)=NEG*x (2 VALU)
__device__ __forceinline__ float lrelu(float x) { return fmaxf(x, NEG * x); }
__device__ __forceinline__ unsigned char f2fp8(float v) {
    return (unsigned char)(__builtin_amdgcn_cvt_pk_fp8_f32(v, v, 0, false) & 0xff);
}
__device__ __forceinline__ float fp82f(unsigned char b) {
    f32x2 p = __builtin_amdgcn_cvt_pk_f32_fp8((int)b, false);
    return p[0];
}

// ---------------- prep: pack W1 + pack W2 + canon small + zero padded counters ----------
__global__ __launch_bounds__(256) void prep_k(const float* __restrict__ W1, const float* __restrict__ W2,
                       const float* __restrict__ s1, const float* __restrict__ d1, const float* __restrict__ b1,
                       const float* __restrict__ s2, const float* __restrict__ d2, const float* __restrict__ b2,
                       unsigned short* __restrict__ W1p, unsigned short* __restrict__ W2p,
                       unsigned short* __restrict__ s1c, unsigned short* __restrict__ d1c,
                       unsigned short* __restrict__ b1c, unsigned short* __restrict__ s2c,
                       unsigned short* __restrict__ d2c, unsigned short* __restrict__ b2c,
                       int* __restrict__ cnt) {
    int b = blockIdx.x;
    if (b < 512) {
        int t = b * 256 + threadIdx.x;            // < 131072 = F_INK*HC
        int k = t / HC, n = t % HC;
        int s = k >> 5, q = (k >> 3) & 3, j = k & 7;
        W1p[((((s << 2) + q) * HC + n) << 3) + j] = f2bf(W1[k * HC + n]);
    } else if (b < 608) {
        int t = (b - 512) * 256 + threadIdx.x;    // < 24576 = HC*OUT_P
        int k = t / OUT_P, n = t % OUT_P;
        int s = k >> 5, q = (k >> 3) & 3, j = k & 7;
        unsigned short v = (n < OUT_C) ? f2bf(W2[k * OUT_C + n]) : (unsigned short)0;
        W2p[((((s << 2) + q) * OUT_P + n) << 3) + j] = v;
    } else if (b == 608) {
        int t = threadIdx.x;
        for (int j = t; j < 512; j += 256) {
            s1c[j] = f2bf(s1[j]); d1c[j] = f2bf(d1[j]); b1c[j] = f2bf(b1[j]);
        }
        if (t < OUT_C) { s2c[t] = f2bf(s2[t]); d2c[t] = f2bf(d2[t]); b2c[t] = f2bf(b2[t]); }
    } else {
        int i = (b - 609) * 256 + threadIdx.x;
        if (i < N_NODES) cnt[i * 16] = 0;   // one counter per 64B line; self-loop implicit
    }
}

// ---------------- FUSED: GEMM1+alpha1 (blocks 0..781) || single-pass edge scatter ----
// Scatter: 782 tiles x 1024 edges, each edge handled exactly ONCE (XCD partition
// filtering removed — the locality hypothesis it served was refuted twice: r7/r9).
// Counters stay 64B-padded (same-line atomic serialization fix), self-loops implicit.
__global__ __launch_bounds__(256) void gemm1_k(const float* __restrict__ x,
                                               const unsigned short* __restrict__ Wp,
                                               const unsigned short* __restrict__ a_s,
                                               const unsigned short* __restrict__ a_d,
                                               unsigned char* __restrict__ h1f8,
                                               float* __restrict__ as1, float* __restrict__ ad1,
                                               const int* __restrict__ ei,
                                               int* __restrict__ cnt, int* __restrict__ srcs) {
    __shared__ unsigned short xs[64 * 264];   // 64 rows x 256 bf16, +8 pad (33 KB)
    int tid = threadIdx.x;
    if (blockIdx.x >= GEMM_NB) {
        // ---- scatter half (single pass) ----
        int chunk = blockIdx.x - GEMM_NB;    // 0 .. CHUNKS-1
        bool is64 = ei_is64(ei);
        int e0 = chunk * 1024 + (tid << 2);
        int s[4], d[4];
        bool vld[4];
        if (chunk < CHUNKS - 1) {
            if (is64) {
                int4 a0 = *reinterpret_cast<const int4*>(ei + 2 * e0);
                int4 a1 = *reinterpret_cast<const int4*>(ei + 2 * e0 + 4);
                int4 c0 = *reinterpret_cast<const int4*>(ei + 2 * N_EDGES + 2 * e0);
                int4 c1 = *reinterpret_cast<const int4*>(ei + 2 * N_EDGES + 2 * e0 + 4);
                s[0] = a0.x; s[1] = a0.z; s[2] = a1.x; s[3] = a1.z;
                d[0] = c0.x; d[1] = c0.z; d[2] = c1.x; d[3] = c1.z;
            } else {
                int4 a0 = *reinterpret_cast<const int4*>(ei + e0);
                int4 c0 = *reinterpret_cast<const int4*>(ei + N_EDGES + e0);
                s[0] = a0.x; s[1] = a0.y; s[2] = a0.z; s[3] = a0.w;
                d[0] = c0.x; d[1] = c0.y; d[2] = c0.z; d[3] = c0.w;
            }
            vld[0] = vld[1] = vld[2] = vld[3] = true;
        } else {
#pragma unroll
            for (int j = 0; j < 4; j++) {
                int e = e0 + j;
                vld[j] = e < N_EDGES;
                int ec = vld[j] ? e : 0;
                s[j] = is64 ? ei[2 * ec] : ei[ec];
                d[j] = is64 ? ei[2 * N_EDGES + 2 * ec] : ei[N_EDGES + ec];
            }
        }
#pragma unroll
        for (int j = 0; j < 4; j++) {
            if (vld[j]) {
                int dj = d[j];
                int pos = atomicAdd(&cnt[dj * 16], 1);
                if (pos < CAP) srcs[(size_t)dj * CAP + pos] = s[j];
            }
        }
        return;
    }
    // ---- GEMM half ----
    int bm = blockIdx.x;
    int row0 = bm * 64;
#pragma unroll
    for (int it = 0; it < 16; it++) {
        int j = tid + it * 256;          // float4 index
        int r = j >> 6;                  // 64 float4 per row
        int c = (j & 63) << 2;           // col (floats)
        int rr = row0 + r; rr = rr < N_NODES ? rr : N_NODES - 1;
        float4 f = *reinterpret_cast<const float4*>(x + (size_t)rr * F_INK + c);
        unsigned int lo = (unsigned int)f2bf(f.x) | ((unsigned int)f2bf(f.y) << 16);
        unsigned int hi = (unsigned int)f2bf(f.z) | ((unsigned int)f2bf(f.w) << 16);
        *reinterpret_cast<uint2*>(&xs[r * 264 + c]) = make_uint2(lo, hi);
    }
    __syncthreads();
    int w = tid >> 6, lane = tid & 63;
    int q = lane >> 4, l16 = lane & 15;
    short8 a[8];
#pragma unroll
    for (int s = 0; s < 8; s++)
        a[s] = *reinterpret_cast<const short8*>(&xs[(w * 16 + l16) * 264 + s * 32 + q * 8]);
    int orow = row0 + w * 16 + q * 4;
#pragma unroll
    for (int bn = 0; bn < 8; bn++) {           // 8 column tiles = 8 heads
        f32x4 acc[4];
#pragma unroll
        for (int t = 0; t < 4; t++) acc[t] = (f32x4){0.f, 0.f, 0.f, 0.f};
#pragma unroll
        for (int s = 0; s < 8; s++) {
#pragma unroll
            for (int t = 0; t < 4; t++) {
                int col = bn * 64 + t * 16 + l16;
                short8 b = *reinterpret_cast<const short8*>(Wp + ((((s << 2) + q) * HC + col) << 3));
                acc[t] = __builtin_amdgcn_mfma_f32_16x16x32_bf16(a[s], b, acc[t], 0, 0, 0);
            }
        }
        float sa0 = 0.f, sa1 = 0.f, sa2 = 0.f, sa3 = 0.f;
        float da0 = 0.f, da1 = 0.f, da2 = 0.f, da3 = 0.f;
#pragma unroll
        for (int t = 0; t < 4; t++) {
            int col = bn * 64 + t * 16 + l16;
            float asc = bf2f(a_s[col]);
            float adc = bf2f(a_d[col]);
            float v0 = acc[t][0], v1 = acc[t][1], v2 = acc[t][2], v3 = acc[t][3];
            sa0 += v0 * asc; da0 += v0 * adc;
            sa1 += v1 * asc; da1 += v1 * adc;
            sa2 += v2 * asc; da2 += v2 * adc;
            sa3 += v3 * asc; da3 += v3 * adc;
            if (orow + 3 < N_NODES) {
                h1f8[(size_t)(orow + 0) * HC + col] = f2fp8(v0);
                h1f8[(size_t)(orow + 1) * HC + col] = f2fp8(v1);
                h1f8[(size_t)(orow + 2) * HC + col] = f2fp8(v2);
                h1f8[(size_t)(orow + 3) * HC + col] = f2fp8(v3);
            } else {
                if (orow + 0 < N_NODES) h1f8[(size_t)(orow + 0) * HC + col] = f2fp8(v0);
                if (orow + 1 < N_NODES) h1f8[(size_t)(orow + 1) * HC + col] = f2fp8(v1);
                if (orow + 2 < N_NODES) h1f8[(size_t)(orow + 2) * HC + col] = f2fp8(v2);
                if (orow + 3 < N_NODES) h1f8[(size_t)(orow + 3) * HC + col] = f2fp8(v3);
            }
        }
#pragma unroll
        for (int m = 1; m < 16; m <<= 1) {
            sa0 += __shfl_xor(sa0, m, 64); sa1 += __shfl_xor(sa1, m, 64);
            sa2 += __shfl_xor(sa2, m, 64); sa3 += __shfl_xor(sa3, m, 64);
            da0 += __shfl_xor(da0, m, 64); da1 += __shfl_xor(da1, m, 64);
            da2 += __shfl_xor(da2, m, 64); da3 += __shfl_xor(da3, m, 64);
        }
        if (l16 < 4) {
            int rr = orow + l16;
            float sav = (l16 == 0) ? sa0 : (l16 == 1) ? sa1 : (l16 == 2) ? sa2 : sa3;
            float dav = (l16 == 0) ? da0 : (l16 == 1) ? da1 : (l16 == 2) ? da2 : da3;
            if (rr < N_NODES) { as1[rr * 8 + bn] = sav; ad1[rr * 8 + bn] = dav; }
        }
    }
}

// ---------------- fused layer-1 aggregation + GEMM2 + alpha2 (h2 fp8, 64B rows) -----------
// Round-4 proven structure (77.5us): 256 thr / 16 dsts, pair-processing (half-wave per
// edge, uint4/lane), LDS-staged buckets, 8-pair-deep gather batches.
#define ACC16(u, wgt)                                                              \
    {                                                                              \
        f32x2 q0 = __builtin_amdgcn_cvt_pk_f32_fp8((int)(u).x, false);             \
        f32x2 q1 = __builtin_amdgcn_cvt_pk_f32_fp8((int)(u).x, true);              \
        f32x2 q2 = __builtin_amdgcn_cvt_pk_f32_fp8((int)(u).y, false);             \
        f32x2 q3 = __builtin_amdgcn_cvt_pk_f32_fp8((int)(u).y, true);              \
        f32x2 q4 = __builtin_amdgcn_cvt_pk_f32_fp8((int)(u).z, false);             \
        f32x2 q5 = __builtin_amdgcn_cvt_pk_f32_fp8((int)(u).z, true);              \
        f32x2 q6 = __builtin_amdgcn_cvt_pk_f32_fp8((int)(u).w, false);             \
        f32x2 q7 = __builtin_amdgcn_cvt_pk_f32_fp8((int)(u).w, true);              \
        f32x2 wv = {(wgt), (wgt)};                                                 \
        ac[0] += wv * q0; ac[1] += wv * q1; ac[2] += wv * q2; ac[3] += wv * q3;    \
        ac[4] += wv * q4; ac[5] += wv * q5; ac[6] += wv * q6; ac[7] += wv * q7;    \
    }

__global__ __launch_bounds__(256) void agg1_k(const unsigned char* __restrict__ h1f8,
                                              const float* __restrict__ as1,
                                              const float* __restrict__ ad1,
                                              const int* __restrict__ cnt,
                                              const int* __restrict__ srcs,
                                              const unsigned short* __restrict__ b1,
                                              const unsigned short* __restrict__ W2p,
                                              const unsigned short* __restrict__ a_s2,
                                              const unsigned short* __restrict__ a_d2,
                                              unsigned char* __restrict__ h2f8) {
    __shared__ unsigned short rows[16 * 520];   // 16 rows x 512 bf16, +8 pad (16.6 KB)
    __shared__ int sSrc[16 * CAP];              // staged edge buckets (4 KB)
    __shared__ int sCnt[16];
    __shared__ float sAs[16], sAd[16];
    __shared__ int ctr;
    int tid = threadIdx.x;
    int base = blockIdx.x * 16;
    // stage buckets: 16*CAP ints = 256 int4, one per thread (fully coalesced)
    reinterpret_cast<int4*>(sSrc)[tid] =
        reinterpret_cast<const int4*>(srcs + (size_t)base * CAP)[tid];
    if (tid < 16) {
        int d = cnt[(base + tid) * 16];
        sCnt[tid] = d < CAP ? d : CAP;
        sAs[tid] = 0.f; sAd[tid] = 0.f;
    }
    if (tid == 0) ctr = 0;
    __syncthreads();
    int w = tid >> 6, lane = tid & 63;
    int half = lane >> 5, li = lane & 31;       // li covers ch [li*16, li*16+16)
    int h = li >> 2;                            // head of this lane's slice (16 | 64)
    // bias slice: 16 bf16 = 2 x uint4
    uint4 ub0 = reinterpret_cast<const uint4*>(b1)[li * 2 + 0];
    uint4 ub1 = reinterpret_cast<const uint4*>(b1)[li * 2 + 1];
    for (;;) {
        int rl = 0;
        if (lane == 0) rl = atomicAdd(&ctr, 1);
        rl = __shfl(rl, 0, 64);
        if (rl >= 16) break;
        int wid = base + rl;
        float adv = ad1[wid * 8 + h];
        const int* sp = sSrc + rl * CAP;
        int deg = sCnt[rl];
        f32x2 ac[8];
#pragma unroll
        for (int k = 0; k < 8; k++) ac[k] = (f32x2){0.f, 0.f};
        float sumw = 0.f;
        {   // pair 0: half0 = implicit self-loop, half1 = first real edge (if any)
            int s = half ? (deg > 0 ? sp[0] : wid) : wid;
            float A = as1[s * 8 + h];
            uint4 u = reinterpret_cast<const uint4*>(h1f8 + (size_t)s * HC)[li];
            float wj = (half && deg == 0) ? 0.f : __expf(lrelu(A + adv));
            sumw += wj;
            ACC16(u, wj)
        }
        int v = 1;                              // remaining edges: bucket idx 1..deg-1
        for (; v + 16 <= deg; v += 16) {        // deep tier: 8 pairs = 16 edges
            int s[8]; float A[8]; uint4 u[8];
#pragma unroll
            for (int j = 0; j < 8; j++) s[j] = sp[v + 2 * j + half];
#pragma unroll
            for (int j = 0; j < 8; j++) A[j] = as1[s[j] * 8 + h];
#pragma unroll
            for (int j = 0; j < 8; j++)
                u[j] = reinterpret_cast<const uint4*>(h1f8 + (size_t)s[j] * HC)[li];
#pragma unroll
            for (int j = 0; j < 8; j++) {
                float wj = __expf(lrelu(A[j] + adv));
                sumw += wj;
                ACC16(u[j], wj)
            }
        }
        for (; v + 8 <= deg; v += 8) {          // 4 pairs = 8 edges
            int s[4]; float A[4]; uint4 u[4];
#pragma unroll
            for (int j = 0; j < 4; j++) s[j] = sp[v + 2 * j + half];
#pragma unroll
            for (int j = 0; j < 4; j++) A[j] = as1[s[j] * 8 + h];
#pragma unroll
            for (int j = 0; j < 4; j++)
                u[j] = reinterpret_cast<const uint4*>(h1f8 + (size_t)s[j] * HC)[li];
#pragma unroll
            for (int j = 0; j < 4; j++) {
                float wj = __expf(lrelu(A[j] + adv));
                sumw += wj;
                ACC16(u[j], wj)
            }
        }
        for (; v + 4 <= deg; v += 4) {          // 2 pairs = 4 edges
            int s[2]; float A[2]; uint4 u[2];
#pragma unroll
            for (int j = 0; j < 2; j++) s[j] = sp[v + 2 * j + half];
#pragma unroll
            for (int j = 0; j < 2; j++) A[j] = as1[s[j] * 8 + h];
#pragma unroll
            for (int j = 0; j < 2; j++)
                u[j] = reinterpret_cast<const uint4*>(h1f8 + (size_t)s[j] * HC)[li];
#pragma unroll
            for (int j = 0; j < 2; j++) {
                float wj = __expf(lrelu(A[j] + adv));
                sumw += wj;
                ACC16(u[j], wj)
            }
        }
        for (; v < deg; v += 2) {               // tail pairs (maybe half-masked)
            int vv = v + half;
            bool ok = vv < deg;
            int s = ok ? sp[vv] : wid;
            float A = as1[s * 8 + h];
            uint4 u = reinterpret_cast<const uint4*>(h1f8 + (size_t)s * HC)[li];
            float wj = ok ? __expf(lrelu(A + adv)) : 0.f;
            sumw += wj;
            ACC16(u, wj)
        }
        // fold the two half-waves
        sumw += __shfl_xor(sumw, 32, 64);
#pragma unroll
        for (int k = 0; k < 8; k++) {
            ac[k][0] += __shfl_xor(ac[k][0], 32, 64);
            ac[k][1] += __shfl_xor(ac[k][1], 32, 64);
        }
        float inv = 1.f / sumw;
        f32x2 n0 = half ? ac[4] : ac[0];
        f32x2 n1 = half ? ac[5] : ac[1];
        f32x2 n2 = half ? ac[6] : ac[2];
        f32x2 n3 = half ? ac[7] : ac[3];
        uint4 ubh = half ? ub1 : ub0;
        float o0 = fmaxf(n0[0] * inv + bflo(ubh.x), 0.f);
        float o1 = fmaxf(n0[1] * inv + bfhi(ubh.x), 0.f);
        float o2 = fmaxf(n1[0] * inv + bflo(ubh.y), 0.f);
        float o3 = fmaxf(n1[1] * inv + bfhi(ubh.y), 0.f);
        float o4 = fmaxf(n2[0] * inv + bflo(ubh.z), 0.f);
        float o5 = fmaxf(n2[1] * inv + bfhi(ubh.z), 0.f);
        float o6 = fmaxf(n3[0] * inv + bflo(ubh.w), 0.f);
        float o7 = fmaxf(n3[1] * inv + bfhi(ubh.w), 0.f);
        uint4 r;
        r.x = (unsigned int)f2bf(o0) | ((unsigned int)f2bf(o1) << 16);
        r.y = (unsigned int)f2bf(o2) | ((unsigned int)f2bf(o3) << 16);
        r.z = (unsigned int)f2bf(o4) | ((unsigned int)f2bf(o5) << 16);
        r.w = (unsigned int)f2bf(o6) | ((unsigned int)f2bf(o7) << 16);
        *reinterpret_cast<uint4*>(&rows[rl * 520 + li * 16 + half * 8]) = r;
    }
    __syncthreads();
    // Phase 2: h2[16 x 40] = rows @ W2 (fp8 out, 64B stride), + alpha2 partials.
    if (w < 3) {
        int q = lane >> 4, l16 = lane & 15;
        int col = w * 16 + l16;
        f32x4 acc = (f32x4){0.f, 0.f, 0.f, 0.f};
#pragma unroll
        for (int s = 0; s < HC / 32; s++) {
            short8 a = *reinterpret_cast<const short8*>(&rows[l16 * 520 + s * 32 + q * 8]);
            short8 b = *reinterpret_cast<const short8*>(W2p + ((((s << 2) + q) * OUT_P + col) << 3));
            acc = __builtin_amdgcn_mfma_f32_16x16x32_bf16(a, b, acc, 0, 0, 0);
        }
        float sa0 = 0.f, sa1 = 0.f, sa2 = 0.f, sa3 = 0.f;
        float da0 = 0.f, da1 = 0.f, da2 = 0.f, da3 = 0.f;
        if (col < OUT_C) {
            float asc = bf2f(a_s2[col]);
            float adc = bf2f(a_d2[col]);
            sa0 = acc[0] * asc; da0 = acc[0] * adc;
            sa1 = acc[1] * asc; da1 = acc[1] * adc;
            sa2 = acc[2] * asc; da2 = acc[2] * adc;
            sa3 = acc[3] * asc; da3 = acc[3] * adc;
#pragma unroll
            for (int r = 0; r < 4; r++)
                h2f8[(size_t)(base + q * 4 + r) * 64 + col] = f2fp8(acc[r]);
        }
#pragma unroll
        for (int m = 1; m < 16; m <<= 1) {
            sa0 += __shfl_xor(sa0, m, 64); sa1 += __shfl_xor(sa1, m, 64);
            sa2 += __shfl_xor(sa2, m, 64); sa3 += __shfl_xor(sa3, m, 64);
            da0 += __shfl_xor(da0, m, 64); da1 += __shfl_xor(da1, m, 64);
            da2 += __shfl_xor(da2, m, 64); da3 += __shfl_xor(da3, m, 64);
        }
        if (l16 < 4) {
            int rr = q * 4 + l16;
            float sav = (l16 == 0) ? sa0 : (l16 == 1) ? sa1 : (l16 == 2) ? sa2 : sa3;
            float dav = (l16 == 0) ? da0 : (l16 == 1) ? da1 : (l16 == 2) ? da2 : da3;
            atomicAdd(&sAs[rr], sav);
            atomicAdd(&sAd[rr], dav);
        }
    }
    __syncthreads();
    if (tid < 16) {
        unsigned char* r = h2f8 + (size_t)(base + tid) * 64;
        *reinterpret_cast<float*>(r + 40) = sAs[tid];   // alpha2_src logit
        *reinterpret_cast<float*>(r + 44) = sAd[tid];   // alpha2_dst logit
    }
}

// ---------------- layer-2 aggregation + log_softmax (fp8 h2 gather, fp32 out) ----------
__global__ __launch_bounds__(256) void agg2_k(const unsigned char* __restrict__ h2f8,
                                              const int* __restrict__ cnt,
                                              const int* __restrict__ srcs,
                                              const unsigned short* __restrict__ b2,
                                              float* __restrict__ outp) {
    __shared__ int sSrc[4 * CAP];   // 1 KB
    __shared__ int sCnt[4];
    int tid = threadIdx.x;
    int base = blockIdx.x * 4;      // grid = 12500, 4 dsts/block exactly
    if (tid < 64)
        reinterpret_cast<int4*>(sSrc)[tid] =
            reinterpret_cast<const int4*>(srcs + (size_t)base * CAP)[tid];
    if (tid < 4) {
        int d = cnt[(base + tid) * 16];
        sCnt[tid] = d < CAP ? d : CAP;
    }
    __syncthreads();
    int w = tid >> 6;
    int wid = base + w;
    int lane = tid & 63;
    bool act = lane < OUT_C;
    int lclamp = act ? lane : 0;
    const unsigned char* rd = h2f8 + (size_t)wid * 64;
    float adv = *reinterpret_cast<const float*>(rd + 44);
    float acc, sumw;
    {   // implicit self-loop
        float w0 = __expf(lrelu(*reinterpret_cast<const float*>(rd + 40) + adv));
        sumw = w0;
        acc = w0 * fp82f(rd[lclamp]);
    }
    const int* sp = sSrc + w * CAP;
    int deg = sCnt[w];
    int v = 0;
    for (; v + 8 <= deg; v += 8) {
        const unsigned char* r[8];
        float A[8];
        unsigned char c[8];
#pragma unroll
        for (int j = 0; j < 8; j++) r[j] = h2f8 + (size_t)sp[v + j] * 64;
#pragma unroll
        for (int j = 0; j < 8; j++) A[j] = *reinterpret_cast<const float*>(r[j] + 40);
#pragma unroll
        for (int j = 0; j < 8; j++) c[j] = r[j][lclamp];
#pragma unroll
        for (int j = 0; j < 8; j++) {
            float wj = __expf(lrelu(A[j] + adv));
            sumw += wj;
            acc += wj * fp82f(c[j]);
        }
    }
    for (; v + 4 <= deg; v += 4) {
        const unsigned char* r[4];
        float A[4];
        unsigned char c[4];
#pragma unroll
        for (int j = 0; j < 4; j++) r[j] = h2f8 + (size_t)sp[v + j] * 64;
#pragma unroll
        for (int j = 0; j < 4; j++) A[j] = *reinterpret_cast<const float*>(r[j] + 40);
#pragma unroll
        for (int j = 0; j < 4; j++) c[j] = r[j][lclamp];
#pragma unroll
        for (int j = 0; j < 4; j++) {
            float wj = __expf(lrelu(A[j] + adv));
            sumw += wj;
            acc += wj * fp82f(c[j]);
        }
    }
    for (; v < deg; v++) {
        const unsigned char* r0 = h2f8 + (size_t)sp[v] * 64;
        float w0 = __expf(lrelu(*reinterpret_cast<const float*>(r0 + 40) + adv));
        sumw += w0;
        acc += w0 * fp82f(r0[lclamp]);
    }
    float o = acc / sumw + bf2f(b2[lclamp]);
    float mval = act ? o : -1e30f;
#pragma unroll
    for (int m = 32; m >= 1; m >>= 1) mval = fmaxf(mval, __shfl_xor(mval, m, 64));
    float ex = act ? __expf(o - mval) : 0.f;
#pragma unroll
    for (int m = 32; m >= 1; m >>= 1) ex += __shfl_xor(ex, m, 64);
    float res = o - mval - __logf(ex);
    if (act) outp[(size_t)wid * OUT_C + lane] = res;
}

extern "C" void kernel_launch(void* const* d_in, const int* in_sizes, int n_in,
                              void* d_out, int out_size, void* d_ws, size_t ws_size,
                              hipStream_t stream) {
    const float* x      = (const float*)d_in[0];
    const int*   ei     = (const int*)d_in[1];
    const float* W1     = (const float*)d_in[2];
    const float* as1raw = (const float*)d_in[3];
    const float* ad1raw = (const float*)d_in[4];
    const float* b1raw  = (const float*)d_in[5];
    const float* W2     = (const float*)d_in[6];
    const float* as2raw = (const float*)d_in[7];
    const float* ad2raw = (const float*)d_in[8];
    const float* b2raw  = (const float*)d_in[9];
    float* out = (float*)d_out;

    char* p = (char*)d_ws;
    auto alloc = [&](size_t bytes) -> char* {
        char* r = p;
        p += (bytes + 255) & ~(size_t)255;
        return r;
    };
    unsigned short* s1c  = (unsigned short*)alloc(512 * 2);
    unsigned short* d1c  = (unsigned short*)alloc(512 * 2);
    unsigned short* b1c  = (unsigned short*)alloc(512 * 2);
    unsigned short* s2c  = (unsigned short*)alloc(OUT_C * 2);
    unsigned short* d2c  = (unsigned short*)alloc(OUT_C * 2);
    unsigned short* b2c  = (unsigned short*)alloc(OUT_C * 2);
    unsigned char*  h1f8 = (unsigned char*)alloc((size_t)N_NODES * HC);        // 25.6 MB
    unsigned char*  h2f8 = (unsigned char*)alloc((size_t)N_NODES * 64);        // 3.2 MB
    float* as1  = (float*)alloc((size_t)N_NODES * 8 * 4);
    float* ad1  = (float*)alloc((size_t)N_NODES * 8 * 4);
    int* cnt    = (int*)alloc((size_t)N_NODES * 64);                           // padded 64B/ctr
    int* srcs   = (int*)alloc((size_t)N_NODES * CAP * 4);                      // 12.8 MB
    unsigned short* W1p = (unsigned short*)alloc((size_t)F_INK * HC * 2);
    unsigned short* W2p = (unsigned short*)alloc((size_t)HC * OUT_P * 2);
    (void)ws_size; (void)in_sizes; (void)n_in; (void)out_size;

    const int NB = (N_NODES + 255) / 256;  // 196

    prep_k<<<609 + NB, 256, 0, stream>>>(W1, W2, as1raw, ad1raw, b1raw, as2raw, ad2raw, b2raw,
                                         W1p, W2p, s1c, d1c, b1c, s2c, d2c, b2c, cnt);
    gemm1_k<<<GEMM_NB + SCAT_NB, 256, 0, stream>>>(x, W1p, s1c, d1c, h1f8, as1, ad1,
                                                   ei, cnt, srcs);
    agg1_k<<<N_NODES / 16, 256, 0, stream>>>(h1f8, as1, ad1, cnt, srcs, b1c,
                                             W2p, s2c, d2c, h2f8);
    agg2_k<<<N_NODES / 4, 256, 0, stream>>>(h2f8, cnt, srcs, b2c, out);
}